// Round 3
// baseline (230.396 us; speedup 1.0000x reference)
//
#include <hip/hip_runtime.h>
#include <math.h>

#define TAU_F 0.02f
#define NB 64
#define NQ 32
#define NS 256
#define ND 128
#define MAXT 20
#define PERMSTRIDE 320

typedef __bf16 bf16x8 __attribute__((ext_vector_type(8)));
typedef float f32x4 __attribute__((ext_vector_type(4)));

// workspace layout (bytes)
#define OFF_TILEMOD 0u          // 64*20*4 = 5120
#define OFF_TCOUNT  5120u       // 64*4
#define OFF_COUNTER 8192u       // 4
#define OFF_DFRAG   131072u     // 64*20*4*64*8*2 = 5242880
#define OFF_QFRAG   5373952u    // 64*2*4*64*8*2  = 524288
#define OFF_SIMOUT  5898240u    // 64*64*5*4      = 81920

// ---------------------------------------------------------------------------
// Kernel 1 (fused prep + fragment swizzle).
// Blocks 0..63: doc c — modality partition (stable, pad-to-16 by duplicating
//   the segment's first token; max-invariant), then fp32->bf16 swizzle into
//   MFMA A-operand fragment layout.
// Blocks 64..127: query b — fp32->bf16 swizzle into B-operand fragment layout.
// Block 0 also zeroes the tail-block counter for kernel 2.
// ---------------------------------------------------------------------------
__global__ __launch_bounds__(256) void
prep_frag_kernel(const float* __restrict__ qemb, const float* __restrict__ demb,
                 const int* __restrict__ mod,
                 __bf16* __restrict__ qfrag, __bf16* __restrict__ dfrag,
                 int* __restrict__ tilemod_g, int* __restrict__ tcount_g,
                 int* __restrict__ counter) {
    int blk = blockIdx.x;
    int tid = threadIdx.x;
    int lane = tid & 63, wv = tid >> 6;
    int quad = lane >> 4, li = lane & 15;

    if (blk == 0 && tid == 0) *counter = 0;

    if (blk >= NB) {
        // ---- query fragments ----
        int b = blk - NB;
#pragma unroll
        for (int i = 0; i < 2; ++i) {
            int combo = wv * 2 + i;            // 0..7
            int qt = combo >> 2, kc = combo & 3;
            int rowq = qt * 16 + li;
            int k0 = kc * 32 + quad * 8;
            const float* src = qemb + ((size_t)b * NQ + rowq) * ND + k0;
            float4 a = *(const float4*)src;
            float4 bq = *(const float4*)(src + 4);
            bf16x8 o;
            o[0] = (__bf16)a.x;  o[1] = (__bf16)a.y;  o[2] = (__bf16)a.z;  o[3] = (__bf16)a.w;
            o[4] = (__bf16)bq.x; o[5] = (__bf16)bq.y; o[6] = (__bf16)bq.z; o[7] = (__bf16)bq.w;
            *(bf16x8*)(qfrag + (((size_t)(b * 2 + qt) * 4 + kc) * 64 + lane) * 8) = o;
        }
        return;
    }

    // ---- doc partition + fragments ----
    int c = blk;
    __shared__ int smod[NS];
    __shared__ int sperm[PERMSTRIDE];
    __shared__ int counts[5], firsts[5], offs[5], padded[5];
    __shared__ int stilemod[MAXT];
    __shared__ int sT;

    if (tid < 5) { counts[tid] = 0; firsts[tid] = NS; }
    __syncthreads();
    int m_tok = mod[c * NS + tid];
    smod[tid] = m_tok;
    if (m_tok) { atomicAdd(&counts[m_tok], 1); atomicMin(&firsts[m_tok], tid); }
    __syncthreads();
    if (tid == 0) {
        int pos = 0;
        for (int m = 1; m <= 4; ++m) {
            offs[m] = pos;
            int p = (counts[m] + 15) & ~15;
            padded[m] = p;
            for (int t = pos >> 4; t < (pos + p) >> 4; ++t) stilemod[t] = m;
            pos += p;
        }
        sT = pos >> 4;
        tcount_g[c] = pos >> 4;
    }
    __syncthreads();
    // stable rank within modality, scatter into sperm
    if (m_tok) {
        int rank = 0;
        for (int s = 0; s < tid; ++s) rank += (smod[s] == m_tok);
        sperm[offs[m_tok] + rank] = tid;
    }
    // pad slots get the segment's first token (max-invariant duplicate)
    if (tid < 4) {
        int m = tid + 1;
        for (int p = counts[m]; p < padded[m]; ++p) sperm[offs[m] + p] = firsts[m];
    }
    __syncthreads();
    int T = sT;
    if (tid < T) tilemod_g[c * MAXT + tid] = stilemod[tid];

    // fragment swizzle: wave == k-chunk, loop over tiles
    int kc = wv;
    int k0 = kc * 32 + quad * 8;
    for (int t = 0; t < T; ++t) {
        int srow = sperm[t * 16 + li];
        const float* src = demb + ((size_t)c * NS + srow) * ND + k0;
        float4 a = *(const float4*)src;
        float4 bq = *(const float4*)(src + 4);
        bf16x8 o;
        o[0] = (__bf16)a.x;  o[1] = (__bf16)a.y;  o[2] = (__bf16)a.z;  o[3] = (__bf16)a.w;
        o[4] = (__bf16)bq.x; o[5] = (__bf16)bq.y; o[6] = (__bf16)bq.z; o[7] = (__bf16)bq.w;
        *(bf16x8*)(dfrag + (((size_t)(c * MAXT + t) * 4 + kc) * 64 + lane) * 8) = o;
    }
}

// ---------------------------------------------------------------------------
// Kernel 2: main + fused loss tail.
// One block per (c, b-pair). q fragments staged in LDS (16 KB) to keep VGPR
// pressure low; kc-outer / qt-inner MFMA loop, accumulate tile maxima into
// vmax[m][qt] with a wave-uniform switch on tile modality.
// Last block (atomic counter) computes the two-pass logsumexp loss.
// ---------------------------------------------------------------------------
__global__ __launch_bounds__(256, 4) void
main_kernel(const __bf16* __restrict__ dfrag, const __bf16* __restrict__ qfrag,
            const int* __restrict__ tilemod, const int* __restrict__ tcount,
            const int* __restrict__ qmask, const int* __restrict__ qtypes,
            float* __restrict__ simout, int* __restrict__ counter,
            float* __restrict__ out) {
    int blk = blockIdx.x;
    int c = blk >> 5;          // 32 consecutive blocks share a doc
    int bp = blk & 31;
    int b0 = bp * 2;
    int tid = threadIdx.x;
    int lane = tid & 63, wv = tid >> 6;

    // stage q fragments for this block's 2 b's into LDS: [qt][kc][lane] 16B
    __shared__ __bf16 sq[4][4][64 * 8];   // 16 KB
#pragma unroll
    for (int j = 0; j < 4; ++j) {
        int f = tid + 256 * j;            // 0..1023
        int qt = f >> 8, kc = (f >> 6) & 3, ln = f & 63;
        int bg = b0 + (qt >> 1), qtl = qt & 1;
        *(bf16x8*)&sq[qt][kc][ln * 8] =
            *(const bf16x8*)(qfrag + (((size_t)(bg * 2 + qtl) * 4 + kc) * 64 + ln) * 8);
    }
    __syncthreads();

    float vmax[4][4];
#pragma unroll
    for (int m = 0; m < 4; ++m)
#pragma unroll
        for (int qt = 0; qt < 4; ++qt) vmax[m][qt] = -1e30f;

    int T = tcount[c];
    for (int t = wv; t < T; t += 4) {
        f32x4 acc[4] = {{0.f,0.f,0.f,0.f},{0.f,0.f,0.f,0.f},{0.f,0.f,0.f,0.f},{0.f,0.f,0.f,0.f}};
#pragma unroll
        for (int kc = 0; kc < 4; ++kc) {
            bf16x8 af = *(const bf16x8*)(dfrag + (((size_t)(c * MAXT + t) * 4 + kc) * 64 + lane) * 8);
#pragma unroll
            for (int qt = 0; qt < 4; ++qt) {
                bf16x8 bq = *(const bf16x8*)&sq[qt][kc][lane * 8];
                acc[qt] = __builtin_amdgcn_mfma_f32_16x16x32_bf16(af, bq, acc[qt], 0, 0, 0);
            }
        }
        float vv[4];
#pragma unroll
        for (int qt = 0; qt < 4; ++qt) {
            float v = fmaxf(fmaxf(acc[qt][0], acc[qt][1]), fmaxf(acc[qt][2], acc[qt][3]));
            v = fmaxf(v, __shfl_xor(v, 16, 64));
            v = fmaxf(v, __shfl_xor(v, 32, 64));
            vv[qt] = v;   // tile max for query col (lane&15), all lanes valid
        }
        int tm = tilemod[c * MAXT + t];   // wave-uniform
        switch (tm) {
        case 1:
#pragma unroll
            for (int qt = 0; qt < 4; ++qt) vmax[0][qt] = fmaxf(vmax[0][qt], vv[qt]);
            break;
        case 2:
#pragma unroll
            for (int qt = 0; qt < 4; ++qt) vmax[1][qt] = fmaxf(vmax[1][qt], vv[qt]);
            break;
        case 3:
#pragma unroll
            for (int qt = 0; qt < 4; ++qt) vmax[2][qt] = fmaxf(vmax[2][qt], vv[qt]);
            break;
        default:
#pragma unroll
            for (int qt = 0; qt < 4; ++qt) vmax[3][qt] = fmaxf(vmax[3][qt], vv[qt]);
            break;
        }
    }

    __shared__ float lv[4][4][4][16];   // [wave][m][qt][qi]
    if (lane < 16) {
#pragma unroll
        for (int m = 0; m < 4; ++m)
#pragma unroll
            for (int qt = 0; qt < 4; ++qt) lv[wv][m][qt][lane] = vmax[m][qt];
    }
    __syncthreads();
    __shared__ float l2[4][4][16];      // [m][qt][qi]
    {
        int m = tid >> 6, qt = (tid >> 4) & 3, qi = tid & 15;
        float v = fmaxf(fmaxf(lv[0][m][qt][qi], lv[1][m][qt][qi]),
                        fmaxf(lv[2][m][qt][qi], lv[3][m][qt][qi]));
        l2[m][qt][qi] = v;
    }
    __syncthreads();
    if (tid < 64) {
        int bl = tid >> 5, q = tid & 31;
        int qt = bl * 2 + (q >> 4), qi = q & 15;
        float m1 = l2[0][qt][qi], m2 = l2[1][qt][qi];
        float m3 = l2[2][qt][qi], m4 = l2[3][qt][qi];
        int b = b0 + bl;
        float agg = fmaxf(fmaxf(m1, m2), fmaxf(m3, m4));
        float s0 = (qmask[b * NQ + q] != 0) ? agg : 0.f;
        float s1 = m1, s2 = m2, s3 = m3, s4 = m4;
#pragma unroll
        for (int off = 16; off >= 1; off >>= 1) {
            s0 += __shfl_xor(s0, off, 64);
            s1 += __shfl_xor(s1, off, 64);
            s2 += __shfl_xor(s2, off, 64);
            s3 += __shfl_xor(s3, off, 64);
            s4 += __shfl_xor(s4, off, 64);
        }
        if (q == 0) {
            float* o = simout + ((size_t)b * NB + c) * 5;   // UNNORMALIZED sums
            o[0] = s0; o[1] = s1; o[2] = s2; o[3] = s3; o[4] = s4;
        }
    }

    // ---- tail: last block computes the loss ----
    __shared__ int isLast;
    __threadfence();                     // release simout writes (device scope)
    if (tid == 0) {
        int v = atomicAdd(counter, 1);
        isLast = (v == (int)gridDim.x - 1);
    }
    __syncthreads();
    if (!isLast) return;
    __threadfence();                     // acquire all blocks' simout writes

    __shared__ float lloss[NB];
    int r = tid >> 2, i = tid & 3;
    int cnt = 0;
#pragma unroll
    for (int j = 0; j < 8; ++j) cnt += (qmask[r * NQ + i * 8 + j] != 0);
    cnt += __shfl_xor(cnt, 1, 64);
    cnt += __shfl_xor(cnt, 2, 64);
    float scale = 1.0f / (TAU_F * (float)(cnt > 0 ? cnt : 1));

    float mx = -1e30f;
    for (int cc = 0; cc < 16; ++cc) {
        int cx = i * 16 + cc;
        const float* p = simout + ((size_t)r * NB + cx) * 5;
#pragma unroll
        for (int j = 0; j < 5; ++j) {
            if (j == 0 && cx == r) continue;
            mx = fmaxf(mx, p[j] * scale);
        }
    }
    mx = fmaxf(mx, __shfl_xor(mx, 1, 64));
    mx = fmaxf(mx, __shfl_xor(mx, 2, 64));
    float sum = 0.f;
    for (int cc = 0; cc < 16; ++cc) {
        int cx = i * 16 + cc;
        const float* p = simout + ((size_t)r * NB + cx) * 5;
#pragma unroll
        for (int j = 0; j < 5; ++j) {
            if (j == 0 && cx == r) continue;
            sum += expf(p[j] * scale - mx);
        }
    }
    sum += __shfl_xor(sum, 1, 64);
    sum += __shfl_xor(sum, 2, 64);
    if (i == 0) {
        float pos = simout[((size_t)r * NB + r) * 5 + qtypes[r]] * scale;
        lloss[r] = logf(sum) + mx - pos;
    }
    __syncthreads();
    if (tid == 0) {
        float s = 0.f;
        for (int r2 = 0; r2 < NB; ++r2) s += lloss[r2];
        out[0] = s * (1.0f / NB);
    }
}

// ---------------------------------------------------------------------------
extern "C" void kernel_launch(void* const* d_in, const int* in_sizes, int n_in,
                              void* d_out, int out_size, void* d_ws, size_t ws_size,
                              hipStream_t stream) {
    const float* qemb   = (const float*)d_in[0];
    const float* demb   = (const float*)d_in[1];
    const int*   mod    = (const int*)d_in[2];
    const int*   qtypes = (const int*)d_in[3];
    const int*   qmask  = (const int*)d_in[4];

    char* ws = (char*)d_ws;
    int*    tilemod = (int*)(ws + OFF_TILEMOD);
    int*    tcount  = (int*)(ws + OFF_TCOUNT);
    int*    counter = (int*)(ws + OFF_COUNTER);
    __bf16* dfrag   = (__bf16*)(ws + OFF_DFRAG);
    __bf16* qfrag   = (__bf16*)(ws + OFF_QFRAG);
    float*  simout  = (float*)(ws + OFF_SIMOUT);

    prep_frag_kernel<<<2 * NB, 256, 0, stream>>>(qemb, demb, mod, qfrag, dfrag,
                                                 tilemod, tcount, counter);
    main_kernel<<<2048, 256, 0, stream>>>(dfrag, qfrag, tilemod, tcount, qmask,
                                          qtypes, simout, counter, (float*)d_out);
}

// Round 4
// 102.565 us; speedup vs baseline: 2.2463x; 2.2463x over previous
//
#include <hip/hip_runtime.h>
#include <math.h>

#define TAU_F 0.02f
#define NB 64
#define NQ 32
#define NS 256
#define ND 128
#define MAXT 20
#define PERMSTRIDE 320

typedef __bf16 bf16x8 __attribute__((ext_vector_type(8)));
typedef float f32x4 __attribute__((ext_vector_type(4)));

// workspace layout (bytes)
#define OFF_TILEMOD 0u          // 64*20*4 = 5120
#define OFF_TCOUNT  5120u       // 64*4
#define OFF_DFRAG   131072u     // 64*20*4*64*8*2 = 5242880
#define OFF_QFRAG   5373952u    // 64*2*4*64*8*2  = 524288
#define OFF_SIMOUT  5898240u    // 64*64*5*4      = 81920

// ---------------------------------------------------------------------------
// Kernel 1 (fused prep + fragment swizzle).
// Blocks 0..63: doc c — modality partition (stable, pad-to-16 by duplicating
//   the segment's first token; max-invariant), then fp32->bf16 swizzle into
//   MFMA A-operand fragment layout.
// Blocks 64..127: query b — fp32->bf16 swizzle into B-operand fragment layout.
// ---------------------------------------------------------------------------
__global__ __launch_bounds__(256) void
prep_frag_kernel(const float* __restrict__ qemb, const float* __restrict__ demb,
                 const int* __restrict__ mod,
                 __bf16* __restrict__ qfrag, __bf16* __restrict__ dfrag,
                 int* __restrict__ tilemod_g, int* __restrict__ tcount_g) {
    int blk = blockIdx.x;
    int tid = threadIdx.x;
    int lane = tid & 63, wv = tid >> 6;
    int quad = lane >> 4, li = lane & 15;

    if (blk >= NB) {
        // ---- query fragments ----
        int b = blk - NB;
#pragma unroll
        for (int i = 0; i < 2; ++i) {
            int combo = wv * 2 + i;            // 0..7
            int qt = combo >> 2, kc = combo & 3;
            int rowq = qt * 16 + li;
            int k0 = kc * 32 + quad * 8;
            const float* src = qemb + ((size_t)b * NQ + rowq) * ND + k0;
            float4 a = *(const float4*)src;
            float4 bq = *(const float4*)(src + 4);
            bf16x8 o;
            o[0] = (__bf16)a.x;  o[1] = (__bf16)a.y;  o[2] = (__bf16)a.z;  o[3] = (__bf16)a.w;
            o[4] = (__bf16)bq.x; o[5] = (__bf16)bq.y; o[6] = (__bf16)bq.z; o[7] = (__bf16)bq.w;
            *(bf16x8*)(qfrag + (((size_t)(b * 2 + qt) * 4 + kc) * 64 + lane) * 8) = o;
        }
        return;
    }

    // ---- doc partition + fragments ----
    int c = blk;
    __shared__ int smod[NS];
    __shared__ int sperm[PERMSTRIDE];
    __shared__ int counts[5], firsts[5], offs[5], padded[5];
    __shared__ int stilemod[MAXT];
    __shared__ int sT;

    if (tid < 5) { counts[tid] = 0; firsts[tid] = NS; }
    __syncthreads();
    int m_tok = mod[c * NS + tid];
    smod[tid] = m_tok;
    if (m_tok) { atomicAdd(&counts[m_tok], 1); atomicMin(&firsts[m_tok], tid); }
    __syncthreads();
    if (tid == 0) {
        int pos = 0;
        for (int m = 1; m <= 4; ++m) {
            offs[m] = pos;
            int p = (counts[m] + 15) & ~15;
            padded[m] = p;
            for (int t = pos >> 4; t < (pos + p) >> 4; ++t) stilemod[t] = m;
            pos += p;
        }
        sT = pos >> 4;
        tcount_g[c] = pos >> 4;
    }
    __syncthreads();
    // stable rank within modality, scatter into sperm
    if (m_tok) {
        int rank = 0;
        for (int s = 0; s < tid; ++s) rank += (smod[s] == m_tok);
        sperm[offs[m_tok] + rank] = tid;
    }
    // pad slots get the segment's first token (max-invariant duplicate)
    if (tid < 4) {
        int m = tid + 1;
        for (int p = counts[m]; p < padded[m]; ++p) sperm[offs[m] + p] = firsts[m];
    }
    __syncthreads();
    int T = sT;
    if (tid < T) tilemod_g[c * MAXT + tid] = stilemod[tid];

    // fragment swizzle: wave == k-chunk, loop over tiles
    int kc = wv;
    int k0 = kc * 32 + quad * 8;
    for (int t = 0; t < T; ++t) {
        int srow = sperm[t * 16 + li];
        const float* src = demb + ((size_t)c * NS + srow) * ND + k0;
        float4 a = *(const float4*)src;
        float4 bq = *(const float4*)(src + 4);
        bf16x8 o;
        o[0] = (__bf16)a.x;  o[1] = (__bf16)a.y;  o[2] = (__bf16)a.z;  o[3] = (__bf16)a.w;
        o[4] = (__bf16)bq.x; o[5] = (__bf16)bq.y; o[6] = (__bf16)bq.z; o[7] = (__bf16)bq.w;
        *(bf16x8*)(dfrag + (((size_t)(c * MAXT + t) * 4 + kc) * 64 + lane) * 8) = o;
    }
}

// ---------------------------------------------------------------------------
// Kernel 2: main. One block per (c, b-pair). q fragments staged in LDS
// (16 KB) to keep VGPR pressure low; kc-outer / qt-inner MFMA loop,
// accumulate tile maxima into vmax[m][qt] with a wave-uniform switch on
// tile modality. NO device fences here (they nuke L2 reuse — R3 lesson).
// Writes UNNORMALIZED sums (divide by qnorm happens in loss kernel).
// ---------------------------------------------------------------------------
__global__ __launch_bounds__(256, 4) void
main_kernel(const __bf16* __restrict__ dfrag, const __bf16* __restrict__ qfrag,
            const int* __restrict__ tilemod, const int* __restrict__ tcount,
            const int* __restrict__ qmask, float* __restrict__ simout) {
    int blk = blockIdx.x;
    int c = blk >> 5;          // 32 consecutive blocks share a doc
    int bp = blk & 31;
    int b0 = bp * 2;
    int tid = threadIdx.x;
    int lane = tid & 63, wv = tid >> 6;

    // stage q fragments for this block's 2 b's into LDS: [qt][kc][lane] 16B
    __shared__ __bf16 sq[4][4][64 * 8];   // 16 KB
#pragma unroll
    for (int j = 0; j < 4; ++j) {
        int f = tid + 256 * j;            // 0..1023
        int qt = f >> 8, kc = (f >> 6) & 3, ln = f & 63;
        int bg = b0 + (qt >> 1), qtl = qt & 1;
        *(bf16x8*)&sq[qt][kc][ln * 8] =
            *(const bf16x8*)(qfrag + (((size_t)(bg * 2 + qtl) * 4 + kc) * 64 + ln) * 8);
    }
    __syncthreads();

    float vmax[4][4];
#pragma unroll
    for (int m = 0; m < 4; ++m)
#pragma unroll
        for (int qt = 0; qt < 4; ++qt) vmax[m][qt] = -1e30f;

    int T = tcount[c];
    for (int t = wv; t < T; t += 4) {
        f32x4 acc[4] = {{0.f,0.f,0.f,0.f},{0.f,0.f,0.f,0.f},{0.f,0.f,0.f,0.f},{0.f,0.f,0.f,0.f}};
#pragma unroll
        for (int kc = 0; kc < 4; ++kc) {
            bf16x8 af = *(const bf16x8*)(dfrag + (((size_t)(c * MAXT + t) * 4 + kc) * 64 + lane) * 8);
#pragma unroll
            for (int qt = 0; qt < 4; ++qt) {
                bf16x8 bq = *(const bf16x8*)&sq[qt][kc][lane * 8];
                acc[qt] = __builtin_amdgcn_mfma_f32_16x16x32_bf16(af, bq, acc[qt], 0, 0, 0);
            }
        }
        float vv[4];
#pragma unroll
        for (int qt = 0; qt < 4; ++qt) {
            float v = fmaxf(fmaxf(acc[qt][0], acc[qt][1]), fmaxf(acc[qt][2], acc[qt][3]));
            v = fmaxf(v, __shfl_xor(v, 16, 64));
            v = fmaxf(v, __shfl_xor(v, 32, 64));
            vv[qt] = v;   // tile max for query col (lane&15), all lanes valid
        }
        int tm = tilemod[c * MAXT + t];   // wave-uniform
        switch (tm) {
        case 1:
#pragma unroll
            for (int qt = 0; qt < 4; ++qt) vmax[0][qt] = fmaxf(vmax[0][qt], vv[qt]);
            break;
        case 2:
#pragma unroll
            for (int qt = 0; qt < 4; ++qt) vmax[1][qt] = fmaxf(vmax[1][qt], vv[qt]);
            break;
        case 3:
#pragma unroll
            for (int qt = 0; qt < 4; ++qt) vmax[2][qt] = fmaxf(vmax[2][qt], vv[qt]);
            break;
        default:
#pragma unroll
            for (int qt = 0; qt < 4; ++qt) vmax[3][qt] = fmaxf(vmax[3][qt], vv[qt]);
            break;
        }
    }

    __shared__ float lv[4][4][4][16];   // [wave][m][qt][qi]
    if (lane < 16) {
#pragma unroll
        for (int m = 0; m < 4; ++m)
#pragma unroll
            for (int qt = 0; qt < 4; ++qt) lv[wv][m][qt][lane] = vmax[m][qt];
    }
    __syncthreads();
    __shared__ float l2[4][4][16];      // [m][qt][qi]
    {
        int m = tid >> 6, qt = (tid >> 4) & 3, qi = tid & 15;
        float v = fmaxf(fmaxf(lv[0][m][qt][qi], lv[1][m][qt][qi]),
                        fmaxf(lv[2][m][qt][qi], lv[3][m][qt][qi]));
        l2[m][qt][qi] = v;
    }
    __syncthreads();
    if (tid < 64) {
        int bl = tid >> 5, q = tid & 31;
        int qt = bl * 2 + (q >> 4), qi = q & 15;
        float m1 = l2[0][qt][qi], m2 = l2[1][qt][qi];
        float m3 = l2[2][qt][qi], m4 = l2[3][qt][qi];
        int b = b0 + bl;
        float agg = fmaxf(fmaxf(m1, m2), fmaxf(m3, m4));
        float s0 = (qmask[b * NQ + q] != 0) ? agg : 0.f;
        float s1 = m1, s2 = m2, s3 = m3, s4 = m4;
#pragma unroll
        for (int off = 16; off >= 1; off >>= 1) {
            s0 += __shfl_xor(s0, off, 64);
            s1 += __shfl_xor(s1, off, 64);
            s2 += __shfl_xor(s2, off, 64);
            s3 += __shfl_xor(s3, off, 64);
            s4 += __shfl_xor(s4, off, 64);
        }
        if (q == 0) {
            float* o = simout + ((size_t)b * NB + c) * 5;   // UNNORMALIZED sums
            o[0] = s0; o[1] = s1; o[2] = s2; o[3] = s3; o[4] = s4;
        }
    }
}

// ---------------------------------------------------------------------------
// Kernel 3: per-row two-pass logsumexp over 319 logits, mean over rows.
// Row b multiset: {sim[b,c]: c!=b} U {sims[b,c,m]: all c, m=1..4};
// positive = sims[b,b,query_types[b]] (slot index == query_types[b]).
// Computes qnorm from qmask here (simout is unnormalized).
// ---------------------------------------------------------------------------
__global__ void loss_kernel(const float* __restrict__ simout, const int* __restrict__ qtypes,
                            const int* __restrict__ qmask, float* __restrict__ out) {
    __shared__ float lloss[NB];
    int tid = threadIdx.x;
    int r = tid >> 2, i = tid & 3;
    int cnt = 0;
#pragma unroll
    for (int j = 0; j < 8; ++j) cnt += (qmask[r * NQ + i * 8 + j] != 0);
    cnt += __shfl_xor(cnt, 1, 64);
    cnt += __shfl_xor(cnt, 2, 64);
    float scale = 1.0f / (TAU_F * (float)(cnt > 0 ? cnt : 1));

    float mx = -1e30f;
    for (int cc = 0; cc < 16; ++cc) {
        int c = i * 16 + cc;
        const float* p = simout + ((size_t)r * NB + c) * 5;
#pragma unroll
        for (int j = 0; j < 5; ++j) {
            if (j == 0 && c == r) continue;
            mx = fmaxf(mx, p[j] * scale);
        }
    }
    mx = fmaxf(mx, __shfl_xor(mx, 1, 64));
    mx = fmaxf(mx, __shfl_xor(mx, 2, 64));
    float sum = 0.f;
    for (int cc = 0; cc < 16; ++cc) {
        int c = i * 16 + cc;
        const float* p = simout + ((size_t)r * NB + c) * 5;
#pragma unroll
        for (int j = 0; j < 5; ++j) {
            if (j == 0 && c == r) continue;
            sum += expf(p[j] * scale - mx);
        }
    }
    sum += __shfl_xor(sum, 1, 64);
    sum += __shfl_xor(sum, 2, 64);
    if (i == 0) {
        float pos = simout[((size_t)r * NB + r) * 5 + qtypes[r]] * scale;
        lloss[r] = logf(sum) + mx - pos;
    }
    __syncthreads();
    if (tid == 0) {
        float s = 0.f;
        for (int r2 = 0; r2 < NB; ++r2) s += lloss[r2];
        out[0] = s * (1.0f / NB);
    }
}

// ---------------------------------------------------------------------------
extern "C" void kernel_launch(void* const* d_in, const int* in_sizes, int n_in,
                              void* d_out, int out_size, void* d_ws, size_t ws_size,
                              hipStream_t stream) {
    const float* qemb   = (const float*)d_in[0];
    const float* demb   = (const float*)d_in[1];
    const int*   mod    = (const int*)d_in[2];
    const int*   qtypes = (const int*)d_in[3];
    const int*   qmask  = (const int*)d_in[4];

    char* ws = (char*)d_ws;
    int*    tilemod = (int*)(ws + OFF_TILEMOD);
    int*    tcount  = (int*)(ws + OFF_TCOUNT);
    __bf16* dfrag   = (__bf16*)(ws + OFF_DFRAG);
    __bf16* qfrag   = (__bf16*)(ws + OFF_QFRAG);
    float*  simout  = (float*)(ws + OFF_SIMOUT);

    prep_frag_kernel<<<2 * NB, 256, 0, stream>>>(qemb, demb, mod, qfrag, dfrag,
                                                 tilemod, tcount);
    main_kernel<<<2048, 256, 0, stream>>>(dfrag, qfrag, tilemod, tcount, qmask, simout);
    loss_kernel<<<1, 256, 0, stream>>>(simout, qtypes, qmask, (float*)d_out);
}

// Round 5
// 101.809 us; speedup vs baseline: 2.2630x; 1.0074x over previous
//
#include <hip/hip_runtime.h>
#include <math.h>

#define TAU_F 0.02f
#define NB 64
#define NQ 32
#define NS 256
#define ND 128
#define MAXT 12          // max 32-row tiles per doc (sum ceil(c_m/32) <= 11)
#define PERMSTRIDE 384   // MAXT*32

typedef __bf16 bf16x8 __attribute__((ext_vector_type(8)));
typedef float f32x16 __attribute__((ext_vector_type(16)));

// workspace layout (bytes)
#define OFF_TILEMOD 0u          // 64*12*4 = 3072
#define OFF_TCOUNT  4096u       // 64*4
#define OFF_DFRAG   16384u      // 64*12*8*64*16 = 6291456
#define OFF_QFRAG   6307840u    // 64*8*64*16    = 524288
#define OFF_SIMOUT  6832128u    // 64*64*5*4     = 81920

// ---------------------------------------------------------------------------
// Kernel 1 (fused prep + fragment swizzle), pad-to-32 for 32x32x16 MFMA.
// Blocks 0..63: doc c — modality partition (stable, pad segments to x32 by
//   duplicating the segment's first token; max-invariant), then fp32->bf16
//   swizzle into MFMA A-operand layout: A[m=lane&31][k=(lane>>5)*8+j].
// Blocks 64..127: query b — B-operand layout: B[k=(lane>>5)*8+j][n=lane&31].
// ---------------------------------------------------------------------------
__global__ __launch_bounds__(256) void
prep_frag_kernel(const float* __restrict__ qemb, const float* __restrict__ demb,
                 const int* __restrict__ mod,
                 __bf16* __restrict__ qfrag, __bf16* __restrict__ dfrag,
                 int* __restrict__ tilemod_g, int* __restrict__ tcount_g) {
    int blk = blockIdx.x;
    int tid = threadIdx.x;
    int lane = tid & 63, wv = tid >> 6;
    int li32 = lane & 31, kh = lane >> 5;

    if (blk >= NB) {
        // ---- query fragments: lane holds q col li32, k = kc*16 + kh*8 + j ----
        int b = blk - NB;
#pragma unroll
        for (int i = 0; i < 2; ++i) {
            int kc = wv * 2 + i;               // 0..7
            int k0 = kc * 16 + kh * 8;
            const float* src = qemb + ((size_t)b * NQ + li32) * ND + k0;
            float4 a = *(const float4*)src;
            float4 bq = *(const float4*)(src + 4);
            bf16x8 o;
            o[0] = (__bf16)a.x;  o[1] = (__bf16)a.y;  o[2] = (__bf16)a.z;  o[3] = (__bf16)a.w;
            o[4] = (__bf16)bq.x; o[5] = (__bf16)bq.y; o[6] = (__bf16)bq.z; o[7] = (__bf16)bq.w;
            *(bf16x8*)(qfrag + (((size_t)b * 8 + kc) * 64 + lane) * 8) = o;
        }
        return;
    }

    // ---- doc partition + fragments ----
    int c = blk;
    __shared__ int smod[NS];
    __shared__ int sperm[PERMSTRIDE];
    __shared__ int counts[5], firsts[5], offs[5], padded[5];
    __shared__ int stilemod[MAXT];
    __shared__ int sT;

    if (tid < 5) { counts[tid] = 0; firsts[tid] = NS; }
    __syncthreads();
    int m_tok = mod[c * NS + tid];
    smod[tid] = m_tok;
    if (m_tok) { atomicAdd(&counts[m_tok], 1); atomicMin(&firsts[m_tok], tid); }
    __syncthreads();
    if (tid == 0) {
        int pos = 0;
        for (int m = 1; m <= 4; ++m) {
            offs[m] = pos;
            int p = (counts[m] + 31) & ~31;
            padded[m] = p;
            for (int t = pos >> 5; t < (pos + p) >> 5; ++t) stilemod[t] = m;
            pos += p;
        }
        sT = pos >> 5;
        tcount_g[c] = pos >> 5;
    }
    __syncthreads();
    // stable rank within modality, scatter into sperm
    if (m_tok) {
        int rank = 0;
        for (int s = 0; s < tid; ++s) rank += (smod[s] == m_tok);
        sperm[offs[m_tok] + rank] = tid;
    }
    // pad slots get the segment's first token (max-invariant duplicate)
    if (tid < 4) {
        int m = tid + 1;
        for (int p = counts[m]; p < padded[m]; ++p) sperm[offs[m] + p] = firsts[m];
    }
    __syncthreads();
    int T = sT;
    if (tid < T) tilemod_g[c * MAXT + tid] = stilemod[tid];

    // fragment swizzle: lane holds doc row li32 of tile t, k = kc*16+kh*8+j
    for (int kc = wv; kc < 8; kc += 4) {
        int k0 = kc * 16 + kh * 8;
        for (int t = 0; t < T; ++t) {
            int srow = sperm[t * 32 + li32];
            const float* src = demb + ((size_t)c * NS + srow) * ND + k0;
            float4 a = *(const float4*)src;
            float4 bq = *(const float4*)(src + 4);
            bf16x8 o;
            o[0] = (__bf16)a.x;  o[1] = (__bf16)a.y;  o[2] = (__bf16)a.z;  o[3] = (__bf16)a.w;
            o[4] = (__bf16)bq.x; o[5] = (__bf16)bq.y; o[6] = (__bf16)bq.z; o[7] = (__bf16)bq.w;
            *(bf16x8*)(dfrag + (((size_t)(c * MAXT + t) * 8 + kc) * 64 + lane) * 8) = o;
        }
    }
}

// ---------------------------------------------------------------------------
// Kernel 2: main, 32x32x16 MFMA. One block per (c, 2 b's); XCD-swizzled so
// all 32 blocks of a doc land on one XCD (L2 locality heuristic).
// B-operands (queries) live in 64 VGPRs for the whole block — no LDS in the
// K-loop. Per tile: 8 MFMA per b, then 15 v_max + 1 shfl_xor(32) epilogue.
// C/D layout (m74/m101): col=lane&31, row=(reg&3)+8*(reg>>2)+4*(lane>>5).
// ---------------------------------------------------------------------------
__global__ __launch_bounds__(256) void
main_kernel(const __bf16* __restrict__ dfrag, const __bf16* __restrict__ qfrag,
            const int* __restrict__ tilemod, const int* __restrict__ tcount,
            const int* __restrict__ qmask, float* __restrict__ simout) {
    int blk = blockIdx.x;
    // XCD swizzle: xcd = blk&7 gets docs [xcd*8, xcd*8+8)
    int c  = (blk & 7) * 8 + (blk >> 8);
    int bp = (blk >> 3) & 31;
    int b0 = bp * 2;
    int tid = threadIdx.x;
    int lane = tid & 63, wv = tid >> 6;

    // query fragments for 2 b's: 64 VGPRs
    bf16x8 bfrag[2][8];
#pragma unroll
    for (int bi = 0; bi < 2; ++bi)
#pragma unroll
        for (int kc = 0; kc < 8; ++kc)
            bfrag[bi][kc] = *(const bf16x8*)(qfrag + (((size_t)(b0 + bi) * 8 + kc) * 64 + lane) * 8);

    float vmax[2][4];
#pragma unroll
    for (int bi = 0; bi < 2; ++bi)
#pragma unroll
        for (int m = 0; m < 4; ++m) vmax[bi][m] = -1e30f;

    int T = tcount[c];
    for (int t = wv; t < T; t += 4) {
        bf16x8 af[8];
#pragma unroll
        for (int kc = 0; kc < 8; ++kc)
            af[kc] = *(const bf16x8*)(dfrag + (((size_t)(c * MAXT + t) * 8 + kc) * 64 + lane) * 8);
        int tm = tilemod[c * MAXT + t];   // wave-uniform
#pragma unroll
        for (int bi = 0; bi < 2; ++bi) {
            f32x16 acc = {0.f,0.f,0.f,0.f,0.f,0.f,0.f,0.f,0.f,0.f,0.f,0.f,0.f,0.f,0.f,0.f};
#pragma unroll
            for (int kc = 0; kc < 8; ++kc)
                acc = __builtin_amdgcn_mfma_f32_32x32x16_bf16(af[kc], bfrag[bi][kc], acc, 0, 0, 0);
            float v = acc[0];
#pragma unroll
            for (int r = 1; r < 16; ++r) v = fmaxf(v, acc[r]);
            v = fmaxf(v, __shfl_xor(v, 32, 64));   // combine row halves
            // wave-uniform switch on tile modality
            switch (tm) {
            case 1:  vmax[bi][0] = fmaxf(vmax[bi][0], v); break;
            case 2:  vmax[bi][1] = fmaxf(vmax[bi][1], v); break;
            case 3:  vmax[bi][2] = fmaxf(vmax[bi][2], v); break;
            default: vmax[bi][3] = fmaxf(vmax[bi][3], v); break;
            }
        }
    }

    // cross-wave reduce: lv[wave][bi][m][q]
    __shared__ float lv[4][2][4][32];   // 4 KB
    if (lane < 32) {
#pragma unroll
        for (int bi = 0; bi < 2; ++bi)
#pragma unroll
            for (int m = 0; m < 4; ++m) lv[wv][bi][m][lane] = vmax[bi][m];
    }
    __syncthreads();
    __shared__ float l2[2][4][32];      // 1 KB
    {
        int bi = tid >> 7, m = (tid >> 5) & 3, q = tid & 31;
        float v = fmaxf(fmaxf(lv[0][bi][m][q], lv[1][bi][m][q]),
                        fmaxf(lv[2][bi][m][q], lv[3][bi][m][q]));
        l2[bi][m][q] = v;
    }
    __syncthreads();
    if (tid < 64) {
        int bi = tid >> 5, q = tid & 31;
        float m1 = l2[bi][0][q], m2 = l2[bi][1][q];
        float m3 = l2[bi][2][q], m4 = l2[bi][3][q];
        int b = b0 + bi;
        float agg = fmaxf(fmaxf(m1, m2), fmaxf(m3, m4));
        float s0 = (qmask[b * NQ + q] != 0) ? agg : 0.f;
        float s1 = m1, s2 = m2, s3 = m3, s4 = m4;
#pragma unroll
        for (int off = 16; off >= 1; off >>= 1) {   // stays within 32-lane half
            s0 += __shfl_xor(s0, off, 64);
            s1 += __shfl_xor(s1, off, 64);
            s2 += __shfl_xor(s2, off, 64);
            s3 += __shfl_xor(s3, off, 64);
            s4 += __shfl_xor(s4, off, 64);
        }
        if (q == 0) {
            float* o = simout + ((size_t)b * NB + c) * 5;   // UNNORMALIZED sums
            o[0] = s0; o[1] = s1; o[2] = s2; o[3] = s3; o[4] = s4;
        }
    }
}

// ---------------------------------------------------------------------------
// Kernel 3: per-row two-pass logsumexp over 319 logits, mean over rows.
// ---------------------------------------------------------------------------
__global__ void loss_kernel(const float* __restrict__ simout, const int* __restrict__ qtypes,
                            const int* __restrict__ qmask, float* __restrict__ out) {
    __shared__ float lloss[NB];
    int tid = threadIdx.x;
    int r = tid >> 2, i = tid & 3;
    int cnt = 0;
#pragma unroll
    for (int j = 0; j < 8; ++j) cnt += (qmask[r * NQ + i * 8 + j] != 0);
    cnt += __shfl_xor(cnt, 1, 64);
    cnt += __shfl_xor(cnt, 2, 64);
    float scale = 1.0f / (TAU_F * (float)(cnt > 0 ? cnt : 1));

    float mx = -1e30f;
    for (int cc = 0; cc < 16; ++cc) {
        int c = i * 16 + cc;
        const float* p = simout + ((size_t)r * NB + c) * 5;
#pragma unroll
        for (int j = 0; j < 5; ++j) {
            if (j == 0 && c == r) continue;
            mx = fmaxf(mx, p[j] * scale);
        }
    }
    mx = fmaxf(mx, __shfl_xor(mx, 1, 64));
    mx = fmaxf(mx, __shfl_xor(mx, 2, 64));
    float sum = 0.f;
    for (int cc = 0; cc < 16; ++cc) {
        int c = i * 16 + cc;
        const float* p = simout + ((size_t)r * NB + c) * 5;
#pragma unroll
        for (int j = 0; j < 5; ++j) {
            if (j == 0 && c == r) continue;
            sum += expf(p[j] * scale - mx);
        }
    }
    sum += __shfl_xor(sum, 1, 64);
    sum += __shfl_xor(sum, 2, 64);
    if (i == 0) {
        float pos = simout[((size_t)r * NB + r) * 5 + qtypes[r]] * scale;
        lloss[r] = logf(sum) + mx - pos;
    }
    __syncthreads();
    if (tid == 0) {
        float s = 0.f;
        for (int r2 = 0; r2 < NB; ++r2) s += lloss[r2];
        out[0] = s * (1.0f / NB);
    }
}

// ---------------------------------------------------------------------------
extern "C" void kernel_launch(void* const* d_in, const int* in_sizes, int n_in,
                              void* d_out, int out_size, void* d_ws, size_t ws_size,
                              hipStream_t stream) {
    const float* qemb   = (const float*)d_in[0];
    const float* demb   = (const float*)d_in[1];
    const int*   mod    = (const int*)d_in[2];
    const int*   qtypes = (const int*)d_in[3];
    const int*   qmask  = (const int*)d_in[4];

    char* ws = (char*)d_ws;
    int*    tilemod = (int*)(ws + OFF_TILEMOD);
    int*    tcount  = (int*)(ws + OFF_TCOUNT);
    __bf16* dfrag   = (__bf16*)(ws + OFF_DFRAG);
    __bf16* qfrag   = (__bf16*)(ws + OFF_QFRAG);
    float*  simout  = (float*)(ws + OFF_SIMOUT);

    prep_frag_kernel<<<2 * NB, 256, 0, stream>>>(qemb, demb, mod, qfrag, dfrag,
                                                 tilemod, tcount);
    main_kernel<<<2048, 256, 0, stream>>>(dfrag, qfrag, tilemod, tcount, qmask, simout);
    loss_kernel<<<1, 256, 0, stream>>>(simout, qtypes, qmask, (float*)d_out);
}